// Round 10
// baseline (259.243 us; speedup 1.0000x reference)
//
#include <hip/hip_runtime.h>
#include <hip/hip_bf16.h>
#include <cstdint>

// Problem constants
#define B_    8
#define T_    1024
#define S_    1024
#define E_    1024
#define NH_   16
#define HD_   64
#define KVIN_ 256
#define SCALE_ 0.125f   // HEAD_DIM^-0.5 = 64^-0.5

typedef __attribute__((ext_vector_type(8))) short bf16x8;
typedef __attribute__((ext_vector_type(4))) float f32x4;
typedef unsigned short us;

__device__ __forceinline__ us f2bf(float x) {
  union { float f; unsigned u; } v; v.f = x;
  unsigned r = v.u + 0x7fffu + ((v.u >> 16) & 1u);   // RNE
  return (us)(r >> 16);
}

// round-half-up bf16 (2 VALU ops); valid for non-negative finite values (P = exp >= 0)
__device__ __forceinline__ us f2bf_p(float x) {
  union { float f; unsigned u; } v; v.f = x;
  return (us)((v.u + 0x8000u) >> 16);
}

__device__ __forceinline__ void gl_lds16(const us* g, const us* l) {
  __builtin_amdgcn_global_load_lds(
      (const __attribute__((address_space(1))) void*)g,
      (__attribute__((address_space(3))) void*)l, 16, 0, 0);
}

// ---------------- fused prep: fp32->bf16 converts + 4 weight transpose-converts --------
__device__ __forceinline__ void cvt_body8(const float* __restrict__ in,
                                          us* __restrict__ out, int blk, int tid) {
  #pragma unroll
  for (int j = 0; j < 8; ++j) {
    int i = blk * 2048 + j * 256 + tid;
    float4 v = ((const float4*)in)[i];
    ushort4 o;
    o.x = f2bf(v.x); o.y = f2bf(v.y); o.z = f2bf(v.z); o.w = f2bf(v.w);
    ((ushort4*)out)[i] = o;
  }
}

__device__ __forceinline__ void tr_body(const float* __restrict__ W,
                                        us* __restrict__ Wt,
                                        int K, int N, int bx, int by, int tid) {
  __shared__ float t[32][33];
  int n0 = bx * 32, k0 = by * 32;
  int tx = tid & 31, ty = tid >> 5;   // 32x8
  #pragma unroll
  for (int r = 0; r < 32; r += 8)
    t[ty + r][tx] = W[(size_t)(k0 + ty + r) * N + n0 + tx];
  __syncthreads();
  #pragma unroll
  for (int r = 0; r < 32; r += 8)
    Wt[(size_t)(n0 + ty + r) * K + k0 + tx] = f2bf(t[tx][ty + r]);
}

// block ranges: [0,1024) cvt hs, [1024,1280) cvt kv, then tr Wq(1024), Wk(256), Wv(256), Wo(1024)
__global__ __launch_bounds__(256) void k_prep(const float* __restrict__ hs, us* __restrict__ hsb,
                                              const float* __restrict__ kv, us* __restrict__ kvb,
                                              const float* __restrict__ Wq, us* __restrict__ Wqt,
                                              const float* __restrict__ Wk, us* __restrict__ Wkt,
                                              const float* __restrict__ Wv, us* __restrict__ Wvt,
                                              const float* __restrict__ Wo, us* __restrict__ Wot) {
  const int bid = blockIdx.x, tid = threadIdx.x;
  if (bid < 1024) { cvt_body8(hs, hsb, bid, tid); return; }
  if (bid < 1280) { cvt_body8(kv, kvb, bid - 1024, tid); return; }
  int id = bid - 1280;
  if (id < 1024)      tr_body(Wq, Wqt, 1024, 1024, id & 31, id >> 5, tid);
  else if (id < 1280) tr_body(Wk, Wkt, 256, 1024, (id - 1024) & 31, (id - 1024) >> 5, tid);
  else if (id < 1536) tr_body(Wv, Wvt, 256, 1024, (id - 1280) & 31, (id - 1280) >> 5, tid);
  else                tr_body(Wo, Wot, 1024, 1024, (id - 1536) & 31, (id - 1536) >> 5, tid);
}

// ---------------- bf16 bt-GEMM body (single-buffer, 128x64 tile) ----------------
// R0/R1 measured-best form (R5 128x128 tile and R6 2-phase dbuf both regressed the
// total; R9 showed reg-staging loses to global_load_lds on plain GEMM — m151/m249).
// 24 KB single-buffer + (64,16) grid. Do not touch again.
// EPI: 1 = K proj (acc+b -> bf16), 2 = V proj (LDS-transposed coalesced write), 3 = fp32
template <int EPI>
__device__ __forceinline__ void gemm_body(const us* __restrict__ A, int lda,
                                          const us* __restrict__ Bt, int ldb,
                                          const float* __restrict__ bias,
                                          void* __restrict__ Cv, int K) {
  __shared__ us smem[12288];   // 24576 B; EPI==2 reuses as Cs[64][136]
  us* As = smem;
  us* Bs = smem + 128 * 64;
  const int tid = threadIdx.x, lane = tid & 63, w = tid >> 6;
  const int quad = lane >> 4, lc = lane & 15;
  const int m0 = blockIdx.x * 128, n0 = blockIdx.y * 64;
  const int wm = (w >> 1) * 64, wn = (w & 1) * 32;

  f32x4 acc[4][2] = {};

  const int strow = lane >> 3;
  const int stcol = (((lane & 7) ^ ((lane >> 3) & 7)) * 8);
  const us* Ag = A + (size_t)(m0 + w * 32 + strow) * lda + stcol;
  const us* Bg = Bt + (size_t)(n0 + w * 16 + strow) * ldb + stcol;

  for (int k0 = 0; k0 < K; k0 += 64) {
    __syncthreads();
    #pragma unroll
    for (int r = 0; r < 4; ++r)
      gl_lds16(Ag + (size_t)r * 8 * lda + k0, As + (w * 4 + r) * 512);
    #pragma unroll
    for (int r = 0; r < 2; ++r)
      gl_lds16(Bg + (size_t)r * 8 * ldb + k0, Bs + (w * 2 + r) * 512);
    __syncthreads();
    #pragma unroll
    for (int ks = 0; ks < 2; ++ks) {
      bf16x8 af[4], bfr[2];
      #pragma unroll
      for (int i = 0; i < 4; ++i)
        af[i]  = *(const bf16x8*)(As + (wm + i * 16 + lc) * 64 + (((ks * 4 + quad) ^ (lc & 7)) * 8));
      #pragma unroll
      for (int i = 0; i < 2; ++i)
        bfr[i] = *(const bf16x8*)(Bs + (wn + i * 16 + lc) * 64 + (((ks * 4 + quad) ^ (lc & 7)) * 8));
      #pragma unroll
      for (int mt = 0; mt < 4; ++mt)
        #pragma unroll
        for (int nt = 0; nt < 2; ++nt)
          acc[mt][nt] = __builtin_amdgcn_mfma_f32_16x16x32_bf16(af[mt], bfr[nt], acc[mt][nt], 0, 0, 0);
    }
  }

  if constexpr (EPI == 2) {
    __syncthreads();
    #pragma unroll
    for (int nt = 0; nt < 2; ++nt) {
      const float bn = bias[n0 + wn + nt * 16 + lc];
      #pragma unroll
      for (int mt = 0; mt < 4; ++mt)
        #pragma unroll
        for (int r = 0; r < 4; ++r)
          smem[(wn + nt * 16 + lc) * 136 + wm + mt * 16 + quad * 4 + r] =
              f2bf(acc[mt][nt][r] + bn);
    }
    __syncthreads();
    const int nl = tid >> 2, sp = (tid & 3) * 32;
    const int bb = m0 >> 10, sw = m0 & 1023;
    us* dst = (us*)Cv + ((size_t)(bb * 1024) + n0 + nl) * 1024 + sw + sp;
    #pragma unroll
    for (int j = 0; j < 4; ++j) {
      uint4 v = *(const uint4*)(smem + nl * 136 + sp + j * 8);
      *(uint4*)(dst + j * 8) = v;
    }
    return;
  }

  #pragma unroll
  for (int mt = 0; mt < 4; ++mt) {
    #pragma unroll
    for (int nt = 0; nt < 2; ++nt) {
      const int n = n0 + wn + nt * 16 + lc;
      const float bn = bias[n];
      #pragma unroll
      for (int r = 0; r < 4; ++r) {
        const int m = m0 + wm + mt * 16 + quad * 4 + r;
        float v = acc[mt][nt][r] + bn;
        if constexpr (EPI == 1)
          ((us*)Cv)[(size_t)m * E_ + n] = f2bf(v);
        else
          ((float*)Cv)[(size_t)m * E_ + n] = v;
      }
    }
  }
}

// K/V projections in one launch: blockIdx.z picks the GEMM. Grid (64, 16, 2).
__global__ __launch_bounds__(256) void k_proj(const us* __restrict__ kvb,
                                              const us* __restrict__ Wkt,
                                              const us* __restrict__ Wvt,
                                              const float* __restrict__ bk,
                                              const float* __restrict__ bv,
                                              us* __restrict__ Kb,
                                              us* __restrict__ Vtb) {
  if (blockIdx.z == 0) gemm_body<1>(kvb, 256, Wkt, 256, bk, (void*)Kb, 256);
  else                 gemm_body<2>(kvb, 256, Wvt, 256, bv, (void*)Vtb, 256);
}

__global__ __launch_bounds__(256) void k_oproj(const us* __restrict__ Ob,
                                               const us* __restrict__ Wot,
                                               const float* __restrict__ bo,
                                               float* __restrict__ out) {
  gemm_body<3>(Ob, 1024, Wot, 1024, bo, (void*)out, 1024);
}

// ---------------- flash attention with fused Q-projection ----------------
// SESSION-BEST CONFIGURATION (R7, 246.7 us total / k_attn 93.8 us). Ledger:
//  + R1: T14 async-STAGE reg-prefetch on phase-2 K/V (forced reg-staging path): +6%
//  + R7: XCD mapping b = bidx&7 (XCD = batch dedups mask+hs+K/V: FETCH 164->50 MB)
//        and T5 setprio around phase-2 MFMA clusters: +5%
//  - R2/R3: swapped QK^T: bank conflicts 1.1M->3.2M, NET-NEGATIVE
//  - R2: held 32-float mask prefetch across PV: scratch spill (WRITE 16->195 MB)
//  - R8: K/V direct-from-L2 (no LDS): 6x L2 traffic, uncoalesced, 94->235 us.
//        LDS staging = cross-wave reuse + coalescing, not just latency hiding.
//  - R9: T14 reg-staging on phase-1 Q-GEMM: loses to global_load_lds (m151/m249)
// Phase 1: Q-tile GEMM via gl_lds 2-barrier loop; C->A relayout through Ps (per-wave).
// Phase 2: reg-prefetch K/V tile s0+64 under compute of s0; raw s_barrier (no vmcnt
// drain) + lgkmcnt(0) publishes ds_writes; mask loads inside mt-loop init sacc.
// LDS 34816 B -> 4 blocks/CU. No online-max (scores O(1)).
__global__ __launch_bounds__(256, 4) void k_attn(const us* __restrict__ hsb,
                                                 const us* __restrict__ Wqt,
                                                 const float* __restrict__ bq,
                                                 const us* __restrict__ Kg_,
                                                 const us* __restrict__ Vt,
                                                 const float* __restrict__ mask,
                                                 const float* __restrict__ lhm,
                                                 us* __restrict__ O) {
  // layout: [0,4096) Ks | [4096,8192) Vs | [8192,17408) Ps[4][32*72]
  // Q-phase reuse: [0,8192) = A-staging (128x64), [8192,12288) = B-staging (64x64)
  __shared__ us smem[17408];
  us* Ks = smem;
  us* Vs = smem + 4096;
  us* Ps = smem + 8192;          // per wave: + w*2304, 32 rows x stride 72

  const int tid = threadIdx.x, lane = tid & 63, w = tid >> 6;
  const int quad = lane >> 4, lc = lane & 15;
  const int bidx = blockIdx.x;
  const int b = bidx & 7;            // XCD = b: dedups mask, hs AND K/V per XCD
  const int h = (bidx >> 3) & 15;
  const int qt = bidx >> 7;
  const int q0 = qt * 128 + w * 32;  // this wave's 32 q rows start (within b)

  const int strow = lane >> 3;
  const int stcol = (((lane & 7) ^ ((lane >> 3) & 7)) * 8);

  // phase-2 global sources (per-lane, same addresses the old gl_lds DMA used)
  const us* Kgs = Kg_ + ((size_t)(b * 1024) + w * 16 + strow) * 1024 + h * 64 + stcol;
  const us* Vgs = Vt + ((size_t)((b * 16 + h) * 64) + w * 16 + strow) * 1024 + stcol;

  // ---- Phase 1: Q-tile GEMM (M=128 block rows, N=64 head cols, K=1024) ----
  bf16x8 qf[2][2];
  uint4 kr0, kr1, vr0, vr1;      // phase-2 staging regs
  {
    const us* Ag = hsb + (size_t)(b * 1024 + qt * 128 + w * 32 + strow) * 1024 + stcol;
    const us* Bg = Wqt + (size_t)(h * 64 + w * 16 + strow) * 1024 + stcol;
    f32x4 qacc[2][4] = {};
    for (int k0 = 0; k0 < 1024; k0 += 64) {
      __syncthreads();
      #pragma unroll
      for (int r = 0; r < 4; ++r)
        gl_lds16(Ag + (size_t)r * 8 * 1024 + k0, smem + (w * 4 + r) * 512);
      #pragma unroll
      for (int r = 0; r < 2; ++r)
        gl_lds16(Bg + (size_t)r * 8 * 1024 + k0, smem + 8192 + (w * 2 + r) * 512);
      __syncthreads();
      #pragma unroll
      for (int ks = 0; ks < 2; ++ks) {
        bf16x8 af[2], bfr[4];
        #pragma unroll
        for (int i = 0; i < 2; ++i)
          af[i] = *(const bf16x8*)(smem + (w * 32 + i * 16 + lc) * 64 + (((ks * 4 + quad) ^ (lc & 7)) * 8));
        #pragma unroll
        for (int i = 0; i < 4; ++i)
          bfr[i] = *(const bf16x8*)(smem + 8192 + (i * 16 + lc) * 64 + (((ks * 4 + quad) ^ (lc & 7)) * 8));
        #pragma unroll
        for (int mt = 0; mt < 2; ++mt)
          #pragma unroll
          for (int nt = 0; nt < 4; ++nt)
            qacc[mt][nt] = __builtin_amdgcn_mfma_f32_16x16x32_bf16(af[mt], bfr[nt], qacc[mt][nt], 0, 0, 0);
      }
    }
    // issue phase-2 prologue prefetch (s0 = 0 K/V tile) — latency hides under the
    // Ps epilogue roundtrip + first s-loop barrier; raw barrier below does NOT drain it
    kr0 = *(const uint4*)(Kgs);
    kr1 = *(const uint4*)(Kgs + (size_t)8 * 1024);
    vr0 = *(const uint4*)(Vgs);
    vr1 = *(const uint4*)(Vgs + (size_t)8 * 1024);

    // epilogue: (acc + bq)*SCALE -> bf16 into this wave's Ps area (C-layout rows)
    // raw barrier (not __syncthreads): only guards B-staging reads (already complete
    // via lgkmcnt before the MFMAs) vs Ps overwrite — must not drain the prefetch.
    __builtin_amdgcn_s_barrier();
    #pragma unroll
    for (int nt = 0; nt < 4; ++nt) {
      const float bn = bq[h * 64 + nt * 16 + lc];
      #pragma unroll
      for (int mt = 0; mt < 2; ++mt)
        #pragma unroll
        for (int r = 0; r < 4; ++r)
          Ps[w * 2304 + (mt * 16 + quad * 4 + r) * 72 + nt * 16 + lc] =
              f2bf((qacc[mt][nt][r] + bn) * SCALE_);
    }
    // readback is same-wave (Ps is per-wave) — lgkmcnt suffices, no barrier
    #pragma unroll
    for (int mt = 0; mt < 2; ++mt) {
      qf[mt][0] = *(const bf16x8*)(&Ps[w * 2304 + (mt * 16 + lc) * 72 + quad * 8]);
      qf[mt][1] = *(const bf16x8*)(&Ps[w * 2304 + (mt * 16 + lc) * 72 + 32 + quad * 8]);
    }
  }

  // ---- Phase 2: attention (async-STAGE pipeline + setprio) ----
  f32x4 oacc[2][4] = {};
  f32x4 lacc[2] = {};

  bf16x8 ones;
  #pragma unroll
  for (int i = 0; i < 8; ++i) ones[i] = (short)0x3F80;   // bf16 1.0

  const float* mg = mask + ((size_t)(b * 1024 + q0 + quad * 4)) * 1024 + lc;

  for (int s0 = 0; s0 < 1024; s0 += 64) {
    // (1) all waves done READING Ks/Vs from the previous iteration's compute
    __builtin_amdgcn_s_barrier();
    // write staged regs -> LDS (compiler inserts the vmcnt wait for kr/vr here;
    // those loads have had a full compute phase in flight). Contiguous b128
    // per wave (1 KB each) — conflict-free, same layout gl_lds produced.
    *(uint4*)(Ks + (w * 16 + 0) * 64 + lane * 8) = kr0;
    *(uint4*)(Ks + (w * 16 + 8) * 64 + lane * 8) = kr1;
    *(uint4*)(Vs + (w * 16 + 0) * 64 + lane * 8) = vr0;
    *(uint4*)(Vs + (w * 16 + 8) * 64 + lane * 8) = vr1;
    // issue NEXT tile's loads — they fly under this iteration's compute
    if (s0 + 64 < 1024) {
      kr0 = *(const uint4*)(Kgs + (size_t)(s0 + 64) * 1024);
      kr1 = *(const uint4*)(Kgs + (size_t)(s0 + 72) * 1024);
      vr0 = *(const uint4*)(Vgs + (s0 + 64));
      vr1 = *(const uint4*)(Vgs + (size_t)8 * 1024 + (s0 + 64));
    }
    // (2) own ds_writes landed (lgkmcnt counts DS only, not the fresh global loads),
    // then publish cross-wave. "memory" clobber pins the ds_writes/ds_reads ordering.
    asm volatile("s_waitcnt lgkmcnt(0)" ::: "memory");
    __builtin_amdgcn_s_barrier();

    #pragma unroll
    for (int mt = 0; mt < 2; ++mt) {
      // mask values initialize the S accumulator (C operand) — no separate add
      f32x4 sacc[4];
      #pragma unroll
      for (int nt = 0; nt < 4; ++nt)
        #pragma unroll
        for (int r = 0; r < 4; ++r)
          sacc[nt][r] = mg[(size_t)(mt * 16 + r) * 1024 + s0 + nt * 16];

      // S = mask + Q K^T for 16 q-rows x 64 s  (T5: favor this wave while others load)
      __builtin_amdgcn_s_setprio(1);
      #pragma unroll
      for (int ks = 0; ks < 2; ++ks)
        #pragma unroll
        for (int nt = 0; nt < 4; ++nt) {
          bf16x8 kf = *(const bf16x8*)(Ks + (nt * 16 + lc) * 64 + (((ks * 4 + quad) ^ (lc & 7)) * 8));
          sacc[nt] = __builtin_amdgcn_mfma_f32_16x16x32_bf16(qf[mt][ks], kf, sacc[nt], 0, 0, 0);
        }
      __builtin_amdgcn_s_setprio(0);

      // P = exp(S) -> bf16 LDS (padded stride 72)
      #pragma unroll
      for (int nt = 0; nt < 4; ++nt)
        #pragma unroll
        for (int r = 0; r < 4; ++r) {
          float pv = __expf(sacc[nt][r]);
          Ps[w * 2304 + (mt * 16 + quad * 4 + r) * 72 + nt * 16 + lc] = f2bf_p(pv);
        }
    }

    // O += P V ; l += P . 1   (A = Ps, B = Vs / ones)
    __builtin_amdgcn_s_setprio(1);
    #pragma unroll
    for (int ks = 0; ks < 2; ++ks) {
      bf16x8 pf0 = *(const bf16x8*)(&Ps[w * 2304 + (0  + lc) * 72 + ks * 32 + quad * 8]);
      bf16x8 pf1 = *(const bf16x8*)(&Ps[w * 2304 + (16 + lc) * 72 + ks * 32 + quad * 8]);
      lacc[0] = __builtin_amdgcn_mfma_f32_16x16x32_bf16(pf0, ones, lacc[0], 0, 0, 0);
      lacc[1] = __builtin_amdgcn_mfma_f32_16x16x32_bf16(pf1, ones, lacc[1], 0, 0, 0);
      #pragma unroll
      for (int nt = 0; nt < 4; ++nt) {
        bf16x8 vf = *(const bf16x8*)(Vs + (nt * 16 + lc) * 64 + (((ks * 4 + quad) ^ (lc & 7)) * 8));
        oacc[0][nt] = __builtin_amdgcn_mfma_f32_16x16x32_bf16(pf0, vf, oacc[0][nt], 0, 0, 0);
        oacc[1][nt] = __builtin_amdgcn_mfma_f32_16x16x32_bf16(pf1, vf, oacc[1][nt], 0, 0, 0);
      }
    }
    __builtin_amdgcn_s_setprio(0);
  }

  // epilogue: O = (lhm[h]/l) * oacc -> bf16 [b*1024+t][h*64+d]
  const float hm = lhm[h];
  #pragma unroll
  for (int mt = 0; mt < 2; ++mt) {
    us* Og = O + ((size_t)(b * 1024 + q0 + mt * 16 + quad * 4)) * 1024 + h * 64 + lc;
    #pragma unroll
    for (int r = 0; r < 4; ++r) {
      float inv = hm / lacc[mt][r];
      #pragma unroll
      for (int nt = 0; nt < 4; ++nt)
        Og[(size_t)r * 1024 + nt * 16] = f2bf(oacc[mt][nt][r] * inv);
    }
  }
}

extern "C" void kernel_launch(void* const* d_in, const int* in_sizes, int n_in,
                              void* d_out, int out_size, void* d_ws, size_t ws_size,
                              hipStream_t stream) {
  (void)in_sizes; (void)n_in; (void)out_size; (void)ws_size;
  const float* hs   = (const float*)d_in[0];
  const float* kv   = (const float*)d_in[1];
  const float* mask = (const float*)d_in[2];
  const float* lhm  = (const float*)d_in[3];
  const float* Wq   = (const float*)d_in[4];
  const float* bq   = (const float*)d_in[5];
  const float* Wk   = (const float*)d_in[6];
  const float* bk   = (const float*)d_in[7];
  const float* Wv   = (const float*)d_in[8];
  const float* bv   = (const float*)d_in[9];
  const float* Wo   = (const float*)d_in[10];
  const float* bo   = (const float*)d_in[11];
  float* out = (float*)d_out;

  char* p = (char*)d_ws;
  auto alloc = [&](size_t bytes) { char* r = p; p += (bytes + 255) & ~(size_t)255; return r; };
  us* hsb = (us*)alloc((size_t)B_ * T_ * E_ * 2);        // 16 MB
  us* kvb = (us*)alloc((size_t)B_ * S_ * KVIN_ * 2);     // 4 MB
  us* Wqt = (us*)alloc((size_t)E_ * E_ * 2);             // 2 MB
  us* Wkt = (us*)alloc((size_t)E_ * KVIN_ * 2);          // 0.5 MB
  us* Wvt = (us*)alloc((size_t)E_ * KVIN_ * 2);          // 0.5 MB
  us* Wot = (us*)alloc((size_t)E_ * E_ * 2);             // 2 MB
  us* Kb  = (us*)alloc((size_t)B_ * S_ * E_ * 2);        // 16 MB
  us* Vtb = (us*)alloc((size_t)B_ * S_ * E_ * 2);        // 16 MB
  us* Ob  = (us*)alloc((size_t)B_ * T_ * E_ * 2);        // 16 MB

  // 1. fused conversions + weight transposes (1 launch)
  k_prep<<<3840, 256, 0, stream>>>(hs, hsb, kv, kvb, Wq, Wqt, Wk, Wkt, Wv, Wvt, Wo, Wot);

  // 2. K/V projections (z = 0/1); grid (m-panels, n-panels, z)
  k_proj<<<dim3(64, 16, 2), 256, 0, stream>>>(kvb, Wkt, Wvt, bk, bv, Kb, Vtb);

  // 3. attention with fused Q-projection (b fast -> XCD = batch dedups mask+hs+K/V)
  k_attn<<<1024, 256, 0, stream>>>(hsb, Wqt, bq, Kb, Vtb, mask, lhm, Ob);

  // 4. output projection -> fp32
  k_oproj<<<dim3(64, 16), 256, 0, stream>>>(Ob, Wot, bo, out);
}

// Round 12
// 257.841 us; speedup vs baseline: 1.0054x; 1.0054x over previous
//
#include <hip/hip_runtime.h>
#include <hip/hip_bf16.h>
#include <cstdint>

// Problem constants
#define B_    8
#define T_    1024
#define S_    1024
#define E_    1024
#define NH_   16
#define HD_   64
#define KVIN_ 256
#define SCALE_ 0.125f   // HEAD_DIM^-0.5 = 64^-0.5

typedef __attribute__((ext_vector_type(8))) short bf16x8;
typedef __attribute__((ext_vector_type(4))) float f32x4;
typedef unsigned short us;

__device__ __forceinline__ us f2bf(float x) {
  union { float f; unsigned u; } v; v.f = x;
  unsigned r = v.u + 0x7fffu + ((v.u >> 16) & 1u);   // RNE
  return (us)(r >> 16);
}

// round-half-up bf16 (2 VALU ops); valid for non-negative finite values (P = exp >= 0)
__device__ __forceinline__ us f2bf_p(float x) {
  union { float f; unsigned u; } v; v.f = x;
  return (us)((v.u + 0x8000u) >> 16);
}

__device__ __forceinline__ void gl_lds16(const us* g, const us* l) {
  __builtin_amdgcn_global_load_lds(
      (const __attribute__((address_space(1))) void*)g,
      (__attribute__((address_space(3))) void*)l, 16, 0, 0);
}

// ---------------- fused prep: fp32->bf16 converts + 4 weight transpose-converts --------
__device__ __forceinline__ void cvt_body8(const float* __restrict__ in,
                                          us* __restrict__ out, int blk, int tid) {
  #pragma unroll
  for (int j = 0; j < 8; ++j) {
    int i = blk * 2048 + j * 256 + tid;
    float4 v = ((const float4*)in)[i];
    ushort4 o;
    o.x = f2bf(v.x); o.y = f2bf(v.y); o.z = f2bf(v.z); o.w = f2bf(v.w);
    ((ushort4*)out)[i] = o;
  }
}

__device__ __forceinline__ void tr_body(const float* __restrict__ W,
                                        us* __restrict__ Wt,
                                        int K, int N, int bx, int by, int tid) {
  __shared__ float t[32][33];
  int n0 = bx * 32, k0 = by * 32;
  int tx = tid & 31, ty = tid >> 5;   // 32x8
  #pragma unroll
  for (int r = 0; r < 32; r += 8)
    t[ty + r][tx] = W[(size_t)(k0 + ty + r) * N + n0 + tx];
  __syncthreads();
  #pragma unroll
  for (int r = 0; r < 32; r += 8)
    Wt[(size_t)(n0 + ty + r) * K + k0 + tx] = f2bf(t[tx][ty + r]);
}

// block ranges: [0,1024) cvt hs, [1024,1280) cvt kv, then tr Wq(1024), Wk(256), Wv(256), Wo(1024)
__global__ __launch_bounds__(256) void k_prep(const float* __restrict__ hs, us* __restrict__ hsb,
                                              const float* __restrict__ kv, us* __restrict__ kvb,
                                              const float* __restrict__ Wq, us* __restrict__ Wqt,
                                              const float* __restrict__ Wk, us* __restrict__ Wkt,
                                              const float* __restrict__ Wv, us* __restrict__ Wvt,
                                              const float* __restrict__ Wo, us* __restrict__ Wot) {
  const int bid = blockIdx.x, tid = threadIdx.x;
  if (bid < 1024) { cvt_body8(hs, hsb, bid, tid); return; }
  if (bid < 1280) { cvt_body8(kv, kvb, bid - 1024, tid); return; }
  int id = bid - 1280;
  if (id < 1024)      tr_body(Wq, Wqt, 1024, 1024, id & 31, id >> 5, tid);
  else if (id < 1280) tr_body(Wk, Wkt, 256, 1024, (id - 1024) & 31, (id - 1024) >> 5, tid);
  else if (id < 1536) tr_body(Wv, Wvt, 256, 1024, (id - 1280) & 31, (id - 1280) >> 5, tid);
  else                tr_body(Wo, Wot, 1024, 1024, (id - 1536) & 31, (id - 1536) >> 5, tid);
}

// ---------------- bf16 bt-GEMM body (single-buffer, 128x64 tile) ----------------
// R0/R1 measured-best form (R5 128x128 tile and R6 2-phase dbuf both regressed;
// R9: reg-staging loses to global_load_lds on plain GEMM — m151/m249). Do not touch.
// EPI: 1 = K proj (acc+b -> bf16), 2 = V proj (LDS-transposed coalesced write), 3 = fp32
template <int EPI>
__device__ __forceinline__ void gemm_body(const us* __restrict__ A, int lda,
                                          const us* __restrict__ Bt, int ldb,
                                          const float* __restrict__ bias,
                                          void* __restrict__ Cv, int K) {
  __shared__ us smem[12288];   // 24576 B; EPI==2 reuses as Cs[64][136]
  us* As = smem;
  us* Bs = smem + 128 * 64;
  const int tid = threadIdx.x, lane = tid & 63, w = tid >> 6;
  const int quad = lane >> 4, lc = lane & 15;
  const int m0 = blockIdx.x * 128, n0 = blockIdx.y * 64;
  const int wm = (w >> 1) * 64, wn = (w & 1) * 32;

  f32x4 acc[4][2] = {};

  const int strow = lane >> 3;
  const int stcol = (((lane & 7) ^ ((lane >> 3) & 7)) * 8);
  const us* Ag = A + (size_t)(m0 + w * 32 + strow) * lda + stcol;
  const us* Bg = Bt + (size_t)(n0 + w * 16 + strow) * ldb + stcol;

  for (int k0 = 0; k0 < K; k0 += 64) {
    __syncthreads();
    #pragma unroll
    for (int r = 0; r < 4; ++r)
      gl_lds16(Ag + (size_t)r * 8 * lda + k0, As + (w * 4 + r) * 512);
    #pragma unroll
    for (int r = 0; r < 2; ++r)
      gl_lds16(Bg + (size_t)r * 8 * ldb + k0, Bs + (w * 2 + r) * 512);
    __syncthreads();
    #pragma unroll
    for (int ks = 0; ks < 2; ++ks) {
      bf16x8 af[4], bfr[2];
      #pragma unroll
      for (int i = 0; i < 4; ++i)
        af[i]  = *(const bf16x8*)(As + (wm + i * 16 + lc) * 64 + (((ks * 4 + quad) ^ (lc & 7)) * 8));
      #pragma unroll
      for (int i = 0; i < 2; ++i)
        bfr[i] = *(const bf16x8*)(Bs + (wn + i * 16 + lc) * 64 + (((ks * 4 + quad) ^ (lc & 7)) * 8));
      #pragma unroll
      for (int mt = 0; mt < 4; ++mt)
        #pragma unroll
        for (int nt = 0; nt < 2; ++nt)
          acc[mt][nt] = __builtin_amdgcn_mfma_f32_16x16x32_bf16(af[mt], bfr[nt], acc[mt][nt], 0, 0, 0);
    }
  }

  if constexpr (EPI == 2) {
    __syncthreads();
    #pragma unroll
    for (int nt = 0; nt < 2; ++nt) {
      const float bn = bias[n0 + wn + nt * 16 + lc];
      #pragma unroll
      for (int mt = 0; mt < 4; ++mt)
        #pragma unroll
        for (int r = 0; r < 4; ++r)
          smem[(wn + nt * 16 + lc) * 136 + wm + mt * 16 + quad * 4 + r] =
              f2bf(acc[mt][nt][r] + bn);
    }
    __syncthreads();
    const int nl = tid >> 2, sp = (tid & 3) * 32;
    const int bb = m0 >> 10, sw = m0 & 1023;
    us* dst = (us*)Cv + ((size_t)(bb * 1024) + n0 + nl) * 1024 + sw + sp;
    #pragma unroll
    for (int j = 0; j < 4; ++j) {
      uint4 v = *(const uint4*)(smem + nl * 136 + sp + j * 8);
      *(uint4*)(dst + j * 8) = v;
    }
    return;
  }

  #pragma unroll
  for (int mt = 0; mt < 4; ++mt) {
    #pragma unroll
    for (int nt = 0; nt < 2; ++nt) {
      const int n = n0 + wn + nt * 16 + lc;
      const float bn = bias[n];
      #pragma unroll
      for (int r = 0; r < 4; ++r) {
        const int m = m0 + wm + mt * 16 + quad * 4 + r;
        float v = acc[mt][nt][r] + bn;
        if constexpr (EPI == 1)
          ((us*)Cv)[(size_t)m * E_ + n] = f2bf(v);
        else
          ((float*)Cv)[(size_t)m * E_ + n] = v;
      }
    }
  }
}

// K/V projections in one launch: blockIdx.z picks the GEMM. Grid (64, 16, 2).
__global__ __launch_bounds__(256) void k_proj(const us* __restrict__ kvb,
                                              const us* __restrict__ Wkt,
                                              const us* __restrict__ Wvt,
                                              const float* __restrict__ bk,
                                              const float* __restrict__ bv,
                                              us* __restrict__ Kb,
                                              us* __restrict__ Vtb) {
  if (blockIdx.z == 0) gemm_body<1>(kvb, 256, Wkt, 256, bk, (void*)Kb, 256);
  else                 gemm_body<2>(kvb, 256, Wvt, 256, bv, (void*)Vtb, 256);
}

__global__ __launch_bounds__(256) void k_oproj(const us* __restrict__ Ob,
                                               const us* __restrict__ Wot,
                                               const float* __restrict__ bo,
                                               float* __restrict__ out) {
  gemm_body<3>(Ob, 1024, Wot, 1024, bo, (void*)out, 1024);
}

// ---------------- flash attention with fused Q-projection ----------------
// R12 = R10 (session best: 246.7 us total / k_attn 92 us) + ONE fix: the mt=0 mask
// loads are issued BEFORE the kr/vr K/V prefetch loads. vmcnt retires in order
// (m135), so previously consuming the mask (sacc C-operand init, issued AFTER
// kr/vr, pinned by the asm "memory" clobber) forced vmcnt ~0 and DRAINED the K/V
// prefetch at the top of every compute phase, while the mask's own L3 latency
// (~400cy; mask slice > 4MB L2) sat exposed after the barrier. With mask-first
// ordering the mask flies under the ds_write+lgkmcnt+barrier window and the K/V
// prefetch stays outstanding across the full compute (T14 as designed). mt=1's
// mask loads stay in-loop (no clobber between mt groups -> they hoist above mt=0's
// MFMAs). Liveness: +16 VGPR over the staging window only (NOT R2's 32-across-PV
// spill — canary: WRITE_SIZE must stay 16 MB).
// Ledger: +R1 T14 phase-2 prefetch; +R7 b=bidx&7 XCD mapping (FETCH 164->50MB) +
// setprio. Rejected: swapped QK^T (R2/R3), mask-held-across-PV (R2), 128^2/2-phase
// GEMMs (R5/R6), K/V direct-from-L2 (R8), reg-staging Q-GEMM (R9), coop fusion (R11
// launch-failed). LDS 34816 B -> 4 blocks/CU. No online-max (scores O(1)).
__global__ __launch_bounds__(256, 4) void k_attn(const us* __restrict__ hsb,
                                                 const us* __restrict__ Wqt,
                                                 const float* __restrict__ bq,
                                                 const us* __restrict__ Kg_,
                                                 const us* __restrict__ Vt,
                                                 const float* __restrict__ mask,
                                                 const float* __restrict__ lhm,
                                                 us* __restrict__ O) {
  // layout: [0,4096) Ks | [4096,8192) Vs | [8192,17408) Ps[4][32*72]
  // Q-phase reuse: [0,8192) = A-staging (128x64), [8192,12288) = B-staging (64x64)
  __shared__ us smem[17408];
  us* Ks = smem;
  us* Vs = smem + 4096;
  us* Ps = smem + 8192;          // per wave: + w*2304, 32 rows x stride 72

  const int tid = threadIdx.x, lane = tid & 63, w = tid >> 6;
  const int quad = lane >> 4, lc = lane & 15;
  const int bidx = blockIdx.x;
  const int b = bidx & 7;            // XCD = b: dedups mask, hs AND K/V per XCD
  const int h = (bidx >> 3) & 15;
  const int qt = bidx >> 7;
  const int q0 = qt * 128 + w * 32;  // this wave's 32 q rows start (within b)

  const int strow = lane >> 3;
  const int stcol = (((lane & 7) ^ ((lane >> 3) & 7)) * 8);

  // phase-2 global sources (per-lane, same addresses the old gl_lds DMA used)
  const us* Kgs = Kg_ + ((size_t)(b * 1024) + w * 16 + strow) * 1024 + h * 64 + stcol;
  const us* Vgs = Vt + ((size_t)((b * 16 + h) * 64) + w * 16 + strow) * 1024 + stcol;

  // ---- Phase 1: Q-tile GEMM (M=128 block rows, N=64 head cols, K=1024) ----
  bf16x8 qf[2][2];
  uint4 kr0, kr1, vr0, vr1;      // phase-2 staging regs
  {
    const us* Ag = hsb + (size_t)(b * 1024 + qt * 128 + w * 32 + strow) * 1024 + stcol;
    const us* Bg = Wqt + (size_t)(h * 64 + w * 16 + strow) * 1024 + stcol;
    f32x4 qacc[2][4] = {};
    for (int k0 = 0; k0 < 1024; k0 += 64) {
      __syncthreads();
      #pragma unroll
      for (int r = 0; r < 4; ++r)
        gl_lds16(Ag + (size_t)r * 8 * 1024 + k0, smem + (w * 4 + r) * 512);
      #pragma unroll
      for (int r = 0; r < 2; ++r)
        gl_lds16(Bg + (size_t)r * 8 * 1024 + k0, smem + 8192 + (w * 2 + r) * 512);
      __syncthreads();
      #pragma unroll
      for (int ks = 0; ks < 2; ++ks) {
        bf16x8 af[2], bfr[4];
        #pragma unroll
        for (int i = 0; i < 2; ++i)
          af[i] = *(const bf16x8*)(smem + (w * 32 + i * 16 + lc) * 64 + (((ks * 4 + quad) ^ (lc & 7)) * 8));
        #pragma unroll
        for (int i = 0; i < 4; ++i)
          bfr[i] = *(const bf16x8*)(smem + 8192 + (i * 16 + lc) * 64 + (((ks * 4 + quad) ^ (lc & 7)) * 8));
        #pragma unroll
        for (int mt = 0; mt < 2; ++mt)
          #pragma unroll
          for (int nt = 0; nt < 4; ++nt)
            qacc[mt][nt] = __builtin_amdgcn_mfma_f32_16x16x32_bf16(af[mt], bfr[nt], qacc[mt][nt], 0, 0, 0);
      }
    }
    // issue phase-2 prologue prefetch (s0 = 0 K/V tile) — latency hides under the
    // Ps epilogue roundtrip + first s-loop barrier; raw barrier below does NOT drain it
    kr0 = *(const uint4*)(Kgs);
    kr1 = *(const uint4*)(Kgs + (size_t)8 * 1024);
    vr0 = *(const uint4*)(Vgs);
    vr1 = *(const uint4*)(Vgs + (size_t)8 * 1024);

    // epilogue: (acc + bq)*SCALE -> bf16 into this wave's Ps area (C-layout rows)
    // raw barrier (not __syncthreads): only guards B-staging reads (already complete
    // via lgkmcnt before the MFMAs) vs Ps overwrite — must not drain the prefetch.
    __builtin_amdgcn_s_barrier();
    #pragma unroll
    for (int nt = 0; nt < 4; ++nt) {
      const float bn = bq[h * 64 + nt * 16 + lc];
      #pragma unroll
      for (int mt = 0; mt < 2; ++mt)
        #pragma unroll
        for (int r = 0; r < 4; ++r)
          Ps[w * 2304 + (mt * 16 + quad * 4 + r) * 72 + nt * 16 + lc] =
              f2bf((qacc[mt][nt][r] + bn) * SCALE_);
    }
    // readback is same-wave (Ps is per-wave) — lgkmcnt suffices, no barrier
    #pragma unroll
    for (int mt = 0; mt < 2; ++mt) {
      qf[mt][0] = *(const bf16x8*)(&Ps[w * 2304 + (mt * 16 + lc) * 72 + quad * 8]);
      qf[mt][1] = *(const bf16x8*)(&Ps[w * 2304 + (mt * 16 + lc) * 72 + 32 + quad * 8]);
    }
  }

  // ---- Phase 2: attention (async-STAGE pipeline + setprio, mask-first ordering) ----
  f32x4 oacc[2][4] = {};
  f32x4 lacc[2] = {};

  bf16x8 ones;
  #pragma unroll
  for (int i = 0; i < 8; ++i) ones[i] = (short)0x3F80;   // bf16 1.0

  const float* mg = mask + ((size_t)(b * 1024 + q0 + quad * 4)) * 1024 + lc;

  f32x4 sacc0[4];                // mt=0 S accumulator, mask-initialized at iter top

  for (int s0 = 0; s0 < 1024; s0 += 64) {
    // (1) all waves done READING Ks/Vs from the previous iteration's compute
    __builtin_amdgcn_s_barrier();
    // write staged regs -> LDS (compiler inserts the vmcnt wait for kr/vr here;
    // those loads have had a full compute phase in flight). Contiguous b128
    // per wave (1 KB each) — conflict-free.
    *(uint4*)(Ks + (w * 16 + 0) * 64 + lane * 8) = kr0;
    *(uint4*)(Ks + (w * 16 + 8) * 64 + lane * 8) = kr1;
    *(uint4*)(Vs + (w * 16 + 0) * 64 + lane * 8) = vr0;
    *(uint4*)(Vs + (w * 16 + 8) * 64 + lane * 8) = vr1;
    // mt=0 mask loads FIRST (older than kr/vr in vmcnt order): their use-wait
    // leaves the K/V prefetch outstanding; latency hides under lgkmcnt+barrier.
    #pragma unroll
    for (int nt = 0; nt < 4; ++nt)
      #pragma unroll
      for (int r = 0; r < 4; ++r)
        sacc0[nt][r] = mg[(size_t)r * 1024 + s0 + nt * 16];
    // issue NEXT tile's K/V loads — they fly across this iteration's full compute
    if (s0 + 64 < 1024) {
      kr0 = *(const uint4*)(Kgs + (size_t)(s0 + 64) * 1024);
      kr1 = *(const uint4*)(Kgs + (size_t)(s0 + 72) * 1024);
      vr0 = *(const uint4*)(Vgs + (s0 + 64));
      vr1 = *(const uint4*)(Vgs + (size_t)8 * 1024 + (s0 + 64));
    }
    // (2) own ds_writes landed (lgkmcnt counts DS only, not the fresh global loads),
    // then publish cross-wave. "memory" clobber pins the ds_writes/ds_reads ordering
    // AND keeps the mask loads above (ordered before) this point.
    asm volatile("s_waitcnt lgkmcnt(0)" ::: "memory");
    __builtin_amdgcn_s_barrier();

    // ---- mt = 0: S = mask + Q K^T (sacc0 pre-initialized) ----
    __builtin_amdgcn_s_setprio(1);
    #pragma unroll
    for (int ks = 0; ks < 2; ++ks)
      #pragma unroll
      for (int nt = 0; nt < 4; ++nt) {
        bf16x8 kf = *(const bf16x8*)(Ks + (nt * 16 + lc) * 64 + (((ks * 4 + quad) ^ (lc & 7)) * 8));
        sacc0[nt] = __builtin_amdgcn_mfma_f32_16x16x32_bf16(qf[0][ks], kf, sacc0[nt], 0, 0, 0);
      }
    __builtin_amdgcn_s_setprio(0);
    #pragma unroll
    for (int nt = 0; nt < 4; ++nt)
      #pragma unroll
      for (int r = 0; r < 4; ++r) {
        float pv = __expf(sacc0[nt][r]);
        Ps[w * 2304 + (quad * 4 + r) * 72 + nt * 16 + lc] = f2bf_p(pv);
      }

    // ---- mt = 1: mask loads (hoistable above mt=0 MFMAs by the scheduler) ----
    {
      f32x4 sacc[4];
      #pragma unroll
      for (int nt = 0; nt < 4; ++nt)
        #pragma unroll
        for (int r = 0; r < 4; ++r)
          sacc[nt][r] = mg[(size_t)(16 + r) * 1024 + s0 + nt * 16];

      __builtin_amdgcn_s_setprio(1);
      #pragma unroll
      for (int ks = 0; ks < 2; ++ks)
        #pragma unroll
        for (int nt = 0; nt < 4; ++nt) {
          bf16x8 kf = *(const bf16x8*)(Ks + (nt * 16 + lc) * 64 + (((ks * 4 + quad) ^ (lc & 7)) * 8));
          sacc[nt] = __builtin_amdgcn_mfma_f32_16x16x32_bf16(qf[1][ks], kf, sacc[nt], 0, 0, 0);
        }
      __builtin_amdgcn_s_setprio(0);
      #pragma unroll
      for (int nt = 0; nt < 4; ++nt)
        #pragma unroll
        for (int r = 0; r < 4; ++r) {
          float pv = __expf(sacc[nt][r]);
          Ps[w * 2304 + (16 + quad * 4 + r) * 72 + nt * 16 + lc] = f2bf_p(pv);
        }
    }

    // O += P V ; l += P . 1   (A = Ps, B = Vs / ones)
    __builtin_amdgcn_s_setprio(1);
    #pragma unroll
    for (int ks = 0; ks < 2; ++ks) {
      bf16x8 pf0 = *(const bf16x8*)(&Ps[w * 2304 + (0  + lc) * 72 + ks * 32 + quad * 8]);
      bf16x8 pf1 = *(const bf16x8*)(&Ps[w * 2304 + (16 + lc) * 72 + ks * 32 + quad * 8]);
      lacc[0] = __builtin_amdgcn_mfma_f32_16x16x32_bf16(pf0, ones, lacc[0], 0, 0, 0);
      lacc[1] = __builtin_amdgcn_mfma_f32_16x16x32_bf16(pf1, ones, lacc[1], 0, 0, 0);
      #pragma unroll
      for (int nt = 0; nt < 4; ++nt) {
        bf16x8 vf = *(const bf16x8*)(Vs + (nt * 16 + lc) * 64 + (((ks * 4 + quad) ^ (lc & 7)) * 8));
        oacc[0][nt] = __builtin_amdgcn_mfma_f32_16x16x32_bf16(pf0, vf, oacc[0][nt], 0, 0, 0);
        oacc[1][nt] = __builtin_amdgcn_mfma_f32_16x16x32_bf16(pf1, vf, oacc[1][nt], 0, 0, 0);
      }
    }
    __builtin_amdgcn_s_setprio(0);
  }

  // epilogue: O = (lhm[h]/l) * oacc -> bf16 [b*1024+t][h*64+d]
  const float hm = lhm[h];
  #pragma unroll
  for (int mt = 0; mt < 2; ++mt) {
    us* Og = O + ((size_t)(b * 1024 + q0 + mt * 16 + quad * 4)) * 1024 + h * 64 + lc;
    #pragma unroll
    for (int r = 0; r < 4; ++r) {
      float inv = hm / lacc[mt][r];
      #pragma unroll
      for (int nt = 0; nt < 4; ++nt)
        Og[(size_t)r * 1024 + nt * 16] = f2bf(oacc[mt][nt][r] * inv);
    }
  }
}

extern "C" void kernel_launch(void* const* d_in, const int* in_sizes, int n_in,
                              void* d_out, int out_size, void* d_ws, size_t ws_size,
                              hipStream_t stream) {
  (void)in_sizes; (void)n_in; (void)out_size; (void)ws_size;
  const float* hs   = (const float*)d_in[0];
  const float* kv   = (const float*)d_in[1];
  const float* mask = (const float*)d_in[2];
  const float* lhm  = (const float*)d_in[3];
  const float* Wq   = (const float*)d_in[4];
  const float* bq   = (const float*)d_in[5];
  const float* Wk   = (const float*)d_in[6];
  const float* bk   = (const float*)d_in[7];
  const float* Wv   = (const float*)d_in[8];
  const float* bv   = (const float*)d_in[9];
  const float* Wo   = (const float*)d_in[10];
  const float* bo   = (const float*)d_in[11];
  float* out = (float*)d_out;

  char* p = (char*)d_ws;
  auto alloc = [&](size_t bytes) { char* r = p; p += (bytes + 255) & ~(size_t)255; return r; };
  us* hsb = (us*)alloc((size_t)B_ * T_ * E_ * 2);        // 16 MB
  us* kvb = (us*)alloc((size_t)B_ * S_ * KVIN_ * 2);     // 4 MB
  us* Wqt = (us*)alloc((size_t)E_ * E_ * 2);             // 2 MB
  us* Wkt = (us*)alloc((size_t)E_ * KVIN_ * 2);          // 0.5 MB
  us* Wvt = (us*)alloc((size_t)E_ * KVIN_ * 2);          // 0.5 MB
  us* Wot = (us*)alloc((size_t)E_ * E_ * 2);             // 2 MB
  us* Kb  = (us*)alloc((size_t)B_ * S_ * E_ * 2);        // 16 MB
  us* Vtb = (us*)alloc((size_t)B_ * S_ * E_ * 2);        // 16 MB
  us* Ob  = (us*)alloc((size_t)B_ * T_ * E_ * 2);        // 16 MB

  // 1. fused conversions + weight transposes (1 launch)
  k_prep<<<3840, 256, 0, stream>>>(hs, hsb, kv, kvb, Wq, Wqt, Wk, Wkt, Wv, Wvt, Wo, Wot);

  // 2. K/V projections (z = 0/1); grid (m-panels, n-panels, z)
  k_proj<<<dim3(64, 16, 2), 256, 0, stream>>>(kvb, Wkt, Wvt, bk, bv, Kb, Vtb);

  // 3. attention with fused Q-projection (b fast -> XCD = batch dedups mask+hs+K/V)
  k_attn<<<1024, 256, 0, stream>>>(hsb, Wqt, bq, Kb, Vtb, mask, lhm, Ob);

  // 4. output projection -> fp32
  k_oproj<<<dim3(64, 16), 256, 0, stream>>>(Ob, Wot, bo, out);
}

// Round 13
// 247.254 us; speedup vs baseline: 1.0485x; 1.0428x over previous
//
#include <hip/hip_runtime.h>
#include <hip/hip_bf16.h>
#include <cstdint>

// Problem constants
#define B_    8
#define T_    1024
#define S_    1024
#define E_    1024
#define NH_   16
#define HD_   64
#define KVIN_ 256
#define SCALE_ 0.125f   // HEAD_DIM^-0.5 = 64^-0.5

typedef __attribute__((ext_vector_type(8))) short bf16x8;
typedef __attribute__((ext_vector_type(4))) float f32x4;
typedef unsigned short us;

__device__ __forceinline__ us f2bf(float x) {
  union { float f; unsigned u; } v; v.f = x;
  unsigned r = v.u + 0x7fffu + ((v.u >> 16) & 1u);   // RNE
  return (us)(r >> 16);
}

// round-half-up bf16 (2 VALU ops); valid for non-negative finite values (P = exp >= 0)
__device__ __forceinline__ us f2bf_p(float x) {
  union { float f; unsigned u; } v; v.f = x;
  return (us)((v.u + 0x8000u) >> 16);
}

__device__ __forceinline__ void gl_lds16(const us* g, const us* l) {
  __builtin_amdgcn_global_load_lds(
      (const __attribute__((address_space(1))) void*)g,
      (__attribute__((address_space(3))) void*)l, 16, 0, 0);
}

// ---------------- fused prep: fp32->bf16 converts + 4 weight transpose-converts --------
__device__ __forceinline__ void cvt_body8(const float* __restrict__ in,
                                          us* __restrict__ out, int blk, int tid) {
  #pragma unroll
  for (int j = 0; j < 8; ++j) {
    int i = blk * 2048 + j * 256 + tid;
    float4 v = ((const float4*)in)[i];
    ushort4 o;
    o.x = f2bf(v.x); o.y = f2bf(v.y); o.z = f2bf(v.z); o.w = f2bf(v.w);
    ((ushort4*)out)[i] = o;
  }
}

__device__ __forceinline__ void tr_body(const float* __restrict__ W,
                                        us* __restrict__ Wt,
                                        int K, int N, int bx, int by, int tid) {
  __shared__ float t[32][33];
  int n0 = bx * 32, k0 = by * 32;
  int tx = tid & 31, ty = tid >> 5;   // 32x8
  #pragma unroll
  for (int r = 0; r < 32; r += 8)
    t[ty + r][tx] = W[(size_t)(k0 + ty + r) * N + n0 + tx];
  __syncthreads();
  #pragma unroll
  for (int r = 0; r < 32; r += 8)
    Wt[(size_t)(n0 + ty + r) * K + k0 + tx] = f2bf(t[tx][ty + r]);
}

// block ranges: [0,1024) cvt hs, [1024,1280) cvt kv, then tr Wq(1024), Wk(256), Wv(256), Wo(1024)
__global__ __launch_bounds__(256) void k_prep(const float* __restrict__ hs, us* __restrict__ hsb,
                                              const float* __restrict__ kv, us* __restrict__ kvb,
                                              const float* __restrict__ Wq, us* __restrict__ Wqt,
                                              const float* __restrict__ Wk, us* __restrict__ Wkt,
                                              const float* __restrict__ Wv, us* __restrict__ Wvt,
                                              const float* __restrict__ Wo, us* __restrict__ Wot) {
  const int bid = blockIdx.x, tid = threadIdx.x;
  if (bid < 1024) { cvt_body8(hs, hsb, bid, tid); return; }
  if (bid < 1280) { cvt_body8(kv, kvb, bid - 1024, tid); return; }
  int id = bid - 1280;
  if (id < 1024)      tr_body(Wq, Wqt, 1024, 1024, id & 31, id >> 5, tid);
  else if (id < 1280) tr_body(Wk, Wkt, 256, 1024, (id - 1024) & 31, (id - 1024) >> 5, tid);
  else if (id < 1536) tr_body(Wv, Wvt, 256, 1024, (id - 1280) & 31, (id - 1280) >> 5, tid);
  else                tr_body(Wo, Wot, 1024, 1024, (id - 1536) & 31, (id - 1536) >> 5, tid);
}

// ---------------- bf16 bt-GEMM body (single-buffer, 128x64 tile) ----------------
// R0/R1 measured-best form (R5 128x128 tile and R6 2-phase dbuf both regressed;
// R9: reg-staging loses to global_load_lds on plain GEMM — m151/m249). Do not touch.
// EPI: 1 = bf16 (acc+bias), 3 = fp32 (acc+bias)
template <int EPI>
__device__ __forceinline__ void gemm_body(const us* __restrict__ A, int lda,
                                          const us* __restrict__ Bt, int ldb,
                                          const float* __restrict__ bias,
                                          void* __restrict__ Cv, int K) {
  __shared__ us smem[12288];   // 24576 B
  us* As = smem;
  us* Bs = smem + 128 * 64;
  const int tid = threadIdx.x, lane = tid & 63, w = tid >> 6;
  const int quad = lane >> 4, lc = lane & 15;
  const int m0 = blockIdx.x * 128, n0 = blockIdx.y * 64;
  const int wm = (w >> 1) * 64, wn = (w & 1) * 32;

  f32x4 acc[4][2] = {};

  const int strow = lane >> 3;
  const int stcol = (((lane & 7) ^ ((lane >> 3) & 7)) * 8);
  const us* Ag = A + (size_t)(m0 + w * 32 + strow) * lda + stcol;
  const us* Bg = Bt + (size_t)(n0 + w * 16 + strow) * ldb + stcol;

  for (int k0 = 0; k0 < K; k0 += 64) {
    __syncthreads();
    #pragma unroll
    for (int r = 0; r < 4; ++r)
      gl_lds16(Ag + (size_t)r * 8 * lda + k0, As + (w * 4 + r) * 512);
    #pragma unroll
    for (int r = 0; r < 2; ++r)
      gl_lds16(Bg + (size_t)r * 8 * ldb + k0, Bs + (w * 2 + r) * 512);
    __syncthreads();
    #pragma unroll
    for (int ks = 0; ks < 2; ++ks) {
      bf16x8 af[4], bfr[2];
      #pragma unroll
      for (int i = 0; i < 4; ++i)
        af[i]  = *(const bf16x8*)(As + (wm + i * 16 + lc) * 64 + (((ks * 4 + quad) ^ (lc & 7)) * 8));
      #pragma unroll
      for (int i = 0; i < 2; ++i)
        bfr[i] = *(const bf16x8*)(Bs + (wn + i * 16 + lc) * 64 + (((ks * 4 + quad) ^ (lc & 7)) * 8));
      #pragma unroll
      for (int mt = 0; mt < 4; ++mt)
        #pragma unroll
        for (int nt = 0; nt < 2; ++nt)
          acc[mt][nt] = __builtin_amdgcn_mfma_f32_16x16x32_bf16(af[mt], bfr[nt], acc[mt][nt], 0, 0, 0);
    }
  }

  #pragma unroll
  for (int mt = 0; mt < 4; ++mt) {
    #pragma unroll
    for (int nt = 0; nt < 2; ++nt) {
      const int n = n0 + wn + nt * 16 + lc;
      const float bn = bias[n];
      #pragma unroll
      for (int r = 0; r < 4; ++r) {
        const int m = m0 + wm + mt * 16 + quad * 4 + r;
        float v = acc[mt][nt][r] + bn;
        if constexpr (EPI == 1)
          ((us*)Cv)[(size_t)m * E_ + n] = f2bf(v);
        else
          ((float*)Cv)[(size_t)m * E_ + n] = v;
      }
    }
  }
}

// ---------------- R13: fused K+V projection (shared A-tile) ----------------
// Blocks (x,y,0) and (x,y,1) previously loaded the IDENTICAL kvb A-panel. Fused:
// one block, one A-staging, two B-stages (Wk, Wv), two accumulator sets, 32 MFMA
// per K-step (vs 16) — halves A traffic and barrier count per FLOP. Grid (64,16).
// LDS 32 KB: As[128x64] | Bk[64x64] | Bv[64x64]; V epilogue reuses [0,8704) as
// Cs[64][136] after a barrier. K epilogue is register-only (runs first).
__global__ __launch_bounds__(256) void k_proj(const us* __restrict__ kvb,
                                              const us* __restrict__ Wkt,
                                              const us* __restrict__ Wvt,
                                              const float* __restrict__ bk,
                                              const float* __restrict__ bv,
                                              us* __restrict__ Kb,
                                              us* __restrict__ Vtb) {
  __shared__ us smem[16384];   // 32768 B: As 8192 | Bk 4096 | Bv 4096
  us* As  = smem;
  us* Bks = smem + 8192;
  us* Bvs = smem + 12288;
  const int tid = threadIdx.x, lane = tid & 63, w = tid >> 6;
  const int quad = lane >> 4, lc = lane & 15;
  const int m0 = blockIdx.x * 128, n0 = blockIdx.y * 64;
  const int wm = (w >> 1) * 64, wn = (w & 1) * 32;

  f32x4 acck[4][2] = {};
  f32x4 accv[4][2] = {};

  const int strow = lane >> 3;
  const int stcol = (((lane & 7) ^ ((lane >> 3) & 7)) * 8);
  const us* Ag  = kvb + (size_t)(m0 + w * 32 + strow) * 256 + stcol;
  const us* Bkg = Wkt + (size_t)(n0 + w * 16 + strow) * 256 + stcol;
  const us* Bvg = Wvt + (size_t)(n0 + w * 16 + strow) * 256 + stcol;

  for (int k0 = 0; k0 < 256; k0 += 64) {
    __syncthreads();
    #pragma unroll
    for (int r = 0; r < 4; ++r)
      gl_lds16(Ag + (size_t)r * 8 * 256 + k0, As + (w * 4 + r) * 512);
    #pragma unroll
    for (int r = 0; r < 2; ++r) {
      gl_lds16(Bkg + (size_t)r * 8 * 256 + k0, Bks + (w * 2 + r) * 512);
      gl_lds16(Bvg + (size_t)r * 8 * 256 + k0, Bvs + (w * 2 + r) * 512);
    }
    __syncthreads();
    #pragma unroll
    for (int ks = 0; ks < 2; ++ks) {
      bf16x8 af[4], bkf[2], bvf[2];
      #pragma unroll
      for (int i = 0; i < 4; ++i)
        af[i]  = *(const bf16x8*)(As + (wm + i * 16 + lc) * 64 + (((ks * 4 + quad) ^ (lc & 7)) * 8));
      #pragma unroll
      for (int i = 0; i < 2; ++i) {
        bkf[i] = *(const bf16x8*)(Bks + (wn + i * 16 + lc) * 64 + (((ks * 4 + quad) ^ (lc & 7)) * 8));
        bvf[i] = *(const bf16x8*)(Bvs + (wn + i * 16 + lc) * 64 + (((ks * 4 + quad) ^ (lc & 7)) * 8));
      }
      #pragma unroll
      for (int mt = 0; mt < 4; ++mt)
        #pragma unroll
        for (int nt = 0; nt < 2; ++nt) {
          acck[mt][nt] = __builtin_amdgcn_mfma_f32_16x16x32_bf16(af[mt], bkf[nt], acck[mt][nt], 0, 0, 0);
          accv[mt][nt] = __builtin_amdgcn_mfma_f32_16x16x32_bf16(af[mt], bvf[nt], accv[mt][nt], 0, 0, 0);
        }
    }
  }

  // ---- K epilogue (register-only): Kb[m][n] = bf16(acck + bk[n]) ----
  #pragma unroll
  for (int mt = 0; mt < 4; ++mt) {
    #pragma unroll
    for (int nt = 0; nt < 2; ++nt) {
      const int n = n0 + wn + nt * 16 + lc;
      const float bn = bk[n];
      #pragma unroll
      for (int r = 0; r < 4; ++r) {
        const int m = m0 + wm + mt * 16 + quad * 4 + r;
        Kb[(size_t)m * E_ + n] = f2bf(acck[mt][nt][r] + bn);
      }
    }
  }

  // ---- V epilogue (LDS-transpose, coalesced Vtb write) ----
  __syncthreads();   // last staging reads done before Cs overwrites smem
  #pragma unroll
  for (int nt = 0; nt < 2; ++nt) {
    const float bn = bv[n0 + wn + nt * 16 + lc];
    #pragma unroll
    for (int mt = 0; mt < 4; ++mt)
      #pragma unroll
      for (int r = 0; r < 4; ++r)
        smem[(wn + nt * 16 + lc) * 136 + wm + mt * 16 + quad * 4 + r] =
            f2bf(accv[mt][nt][r] + bn);
  }
  __syncthreads();
  const int nl = tid >> 2, sp = (tid & 3) * 32;
  const int bb = m0 >> 10, sw = m0 & 1023;
  us* dst = Vtb + ((size_t)(bb * 1024) + n0 + nl) * 1024 + sw + sp;
  #pragma unroll
  for (int j = 0; j < 4; ++j) {
    uint4 v = *(const uint4*)(smem + nl * 136 + sp + j * 8);
    *(uint4*)(dst + j * 8) = v;
  }
}

__global__ __launch_bounds__(256) void k_oproj(const us* __restrict__ Ob,
                                               const us* __restrict__ Wot,
                                               const float* __restrict__ bo,
                                               float* __restrict__ out) {
  gemm_body<3>(Ob, 1024, Wot, 1024, bo, (void*)out, 1024);
}

// ---------------- flash attention with fused Q-projection ----------------
// Session-best k_attn (R10/R12, ~92 us). Ledger: +R1 T14 phase-2 K/V reg-prefetch;
// +R7 b=bidx&7 XCD mapping (FETCH 164->50MB) + T5 setprio; R12 mask-first ordering
// (neutral, kept). Rejected: swapped QK^T (R2/R3), mask-held-across-PV (R2 spill),
// 128^2/2-phase GEMMs (R5/R6), K/V direct-from-L2 (R8: LDS staging = cross-wave
// reuse + coalescing), reg-staging Q-GEMM (R9), coop fusion (R11 launch-failed),
// micro vmcnt-ordering (R12 null — latency already TLP-hidden).
// LDS 34816 B -> 4 blocks/CU. No online-max (scores O(1)).
__global__ __launch_bounds__(256, 4) void k_attn(const us* __restrict__ hsb,
                                                 const us* __restrict__ Wqt,
                                                 const float* __restrict__ bq,
                                                 const us* __restrict__ Kg_,
                                                 const us* __restrict__ Vt,
                                                 const float* __restrict__ mask,
                                                 const float* __restrict__ lhm,
                                                 us* __restrict__ O) {
  // layout: [0,4096) Ks | [4096,8192) Vs | [8192,17408) Ps[4][32*72]
  // Q-phase reuse: [0,8192) = A-staging (128x64), [8192,12288) = B-staging (64x64)
  __shared__ us smem[17408];
  us* Ks = smem;
  us* Vs = smem + 4096;
  us* Ps = smem + 8192;          // per wave: + w*2304, 32 rows x stride 72

  const int tid = threadIdx.x, lane = tid & 63, w = tid >> 6;
  const int quad = lane >> 4, lc = lane & 15;
  const int bidx = blockIdx.x;
  const int b = bidx & 7;            // XCD = b: dedups mask, hs AND K/V per XCD
  const int h = (bidx >> 3) & 15;
  const int qt = bidx >> 7;
  const int q0 = qt * 128 + w * 32;  // this wave's 32 q rows start (within b)

  const int strow = lane >> 3;
  const int stcol = (((lane & 7) ^ ((lane >> 3) & 7)) * 8);

  // phase-2 global sources (per-lane, same addresses the old gl_lds DMA used)
  const us* Kgs = Kg_ + ((size_t)(b * 1024) + w * 16 + strow) * 1024 + h * 64 + stcol;
  const us* Vgs = Vt + ((size_t)((b * 16 + h) * 64) + w * 16 + strow) * 1024 + stcol;

  // ---- Phase 1: Q-tile GEMM (M=128 block rows, N=64 head cols, K=1024) ----
  bf16x8 qf[2][2];
  uint4 kr0, kr1, vr0, vr1;      // phase-2 staging regs
  {
    const us* Ag = hsb + (size_t)(b * 1024 + qt * 128 + w * 32 + strow) * 1024 + stcol;
    const us* Bg = Wqt + (size_t)(h * 64 + w * 16 + strow) * 1024 + stcol;
    f32x4 qacc[2][4] = {};
    for (int k0 = 0; k0 < 1024; k0 += 64) {
      __syncthreads();
      #pragma unroll
      for (int r = 0; r < 4; ++r)
        gl_lds16(Ag + (size_t)r * 8 * 1024 + k0, smem + (w * 4 + r) * 512);
      #pragma unroll
      for (int r = 0; r < 2; ++r)
        gl_lds16(Bg + (size_t)r * 8 * 1024 + k0, smem + 8192 + (w * 2 + r) * 512);
      __syncthreads();
      #pragma unroll
      for (int ks = 0; ks < 2; ++ks) {
        bf16x8 af[2], bfr[4];
        #pragma unroll
        for (int i = 0; i < 2; ++i)
          af[i] = *(const bf16x8*)(smem + (w * 32 + i * 16 + lc) * 64 + (((ks * 4 + quad) ^ (lc & 7)) * 8));
        #pragma unroll
        for (int i = 0; i < 4; ++i)
          bfr[i] = *(const bf16x8*)(smem + 8192 + (i * 16 + lc) * 64 + (((ks * 4 + quad) ^ (lc & 7)) * 8));
        #pragma unroll
        for (int mt = 0; mt < 2; ++mt)
          #pragma unroll
          for (int nt = 0; nt < 4; ++nt)
            qacc[mt][nt] = __builtin_amdgcn_mfma_f32_16x16x32_bf16(af[mt], bfr[nt], qacc[mt][nt], 0, 0, 0);
      }
    }
    // issue phase-2 prologue prefetch (s0 = 0 K/V tile) — latency hides under the
    // Ps epilogue roundtrip + first s-loop barrier; raw barrier below does NOT drain it
    kr0 = *(const uint4*)(Kgs);
    kr1 = *(const uint4*)(Kgs + (size_t)8 * 1024);
    vr0 = *(const uint4*)(Vgs);
    vr1 = *(const uint4*)(Vgs + (size_t)8 * 1024);

    // epilogue: (acc + bq)*SCALE -> bf16 into this wave's Ps area (C-layout rows)
    // raw barrier (not __syncthreads): only guards B-staging reads (already complete
    // via lgkmcnt before the MFMAs) vs Ps overwrite — must not drain the prefetch.
    __builtin_amdgcn_s_barrier();
    #pragma unroll
    for (int nt = 0; nt < 4; ++nt) {
      const float bn = bq[h * 64 + nt * 16 + lc];
      #pragma unroll
      for (int mt = 0; mt < 2; ++mt)
        #pragma unroll
        for (int r = 0; r < 4; ++r)
          Ps[w * 2304 + (mt * 16 + quad * 4 + r) * 72 + nt * 16 + lc] =
              f2bf((qacc[mt][nt][r] + bn) * SCALE_);
    }
    // readback is same-wave (Ps is per-wave) — lgkmcnt suffices, no barrier
    #pragma unroll
    for (int mt = 0; mt < 2; ++mt) {
      qf[mt][0] = *(const bf16x8*)(&Ps[w * 2304 + (mt * 16 + lc) * 72 + quad * 8]);
      qf[mt][1] = *(const bf16x8*)(&Ps[w * 2304 + (mt * 16 + lc) * 72 + 32 + quad * 8]);
    }
  }

  // ---- Phase 2: attention (async-STAGE pipeline + setprio, mask-first ordering) ----
  f32x4 oacc[2][4] = {};
  f32x4 lacc[2] = {};

  bf16x8 ones;
  #pragma unroll
  for (int i = 0; i < 8; ++i) ones[i] = (short)0x3F80;   // bf16 1.0

  const float* mg = mask + ((size_t)(b * 1024 + q0 + quad * 4)) * 1024 + lc;

  f32x4 sacc0[4];                // mt=0 S accumulator, mask-initialized at iter top

  for (int s0 = 0; s0 < 1024; s0 += 64) {
    // (1) all waves done READING Ks/Vs from the previous iteration's compute
    __builtin_amdgcn_s_barrier();
    // write staged regs -> LDS (compiler inserts the vmcnt wait for kr/vr here;
    // those loads have had a full compute phase in flight). Contiguous b128
    // per wave (1 KB each) — conflict-free.
    *(uint4*)(Ks + (w * 16 + 0) * 64 + lane * 8) = kr0;
    *(uint4*)(Ks + (w * 16 + 8) * 64 + lane * 8) = kr1;
    *(uint4*)(Vs + (w * 16 + 0) * 64 + lane * 8) = vr0;
    *(uint4*)(Vs + (w * 16 + 8) * 64 + lane * 8) = vr1;
    // mt=0 mask loads FIRST (older than kr/vr in vmcnt order)
    #pragma unroll
    for (int nt = 0; nt < 4; ++nt)
      #pragma unroll
      for (int r = 0; r < 4; ++r)
        sacc0[nt][r] = mg[(size_t)r * 1024 + s0 + nt * 16];
    // issue NEXT tile's K/V loads — they fly across this iteration's full compute
    if (s0 + 64 < 1024) {
      kr0 = *(const uint4*)(Kgs + (size_t)(s0 + 64) * 1024);
      kr1 = *(const uint4*)(Kgs + (size_t)(s0 + 72) * 1024);
      vr0 = *(const uint4*)(Vgs + (s0 + 64));
      vr1 = *(const uint4*)(Vgs + (size_t)8 * 1024 + (s0 + 64));
    }
    // (2) own ds_writes landed (lgkmcnt counts DS only, not the fresh global loads),
    // then publish cross-wave. "memory" clobber pins the ds_writes/ds_reads ordering.
    asm volatile("s_waitcnt lgkmcnt(0)" ::: "memory");
    __builtin_amdgcn_s_barrier();

    // ---- mt = 0: S = mask + Q K^T (sacc0 pre-initialized) ----
    __builtin_amdgcn_s_setprio(1);
    #pragma unroll
    for (int ks = 0; ks < 2; ++ks)
      #pragma unroll
      for (int nt = 0; nt < 4; ++nt) {
        bf16x8 kf = *(const bf16x8*)(Ks + (nt * 16 + lc) * 64 + (((ks * 4 + quad) ^ (lc & 7)) * 8));
        sacc0[nt] = __builtin_amdgcn_mfma_f32_16x16x32_bf16(qf[0][ks], kf, sacc0[nt], 0, 0, 0);
      }
    __builtin_amdgcn_s_setprio(0);
    #pragma unroll
    for (int nt = 0; nt < 4; ++nt)
      #pragma unroll
      for (int r = 0; r < 4; ++r) {
        float pv = __expf(sacc0[nt][r]);
        Ps[w * 2304 + (quad * 4 + r) * 72 + nt * 16 + lc] = f2bf_p(pv);
      }

    // ---- mt = 1 ----
    {
      f32x4 sacc[4];
      #pragma unroll
      for (int nt = 0; nt < 4; ++nt)
        #pragma unroll
        for (int r = 0; r < 4; ++r)
          sacc[nt][r] = mg[(size_t)(16 + r) * 1024 + s0 + nt * 16];

      __builtin_amdgcn_s_setprio(1);
      #pragma unroll
      for (int ks = 0; ks < 2; ++ks)
        #pragma unroll
        for (int nt = 0; nt < 4; ++nt) {
          bf16x8 kf = *(const bf16x8*)(Ks + (nt * 16 + lc) * 64 + (((ks * 4 + quad) ^ (lc & 7)) * 8));
          sacc[nt] = __builtin_amdgcn_mfma_f32_16x16x32_bf16(qf[1][ks], kf, sacc[nt], 0, 0, 0);
        }
      __builtin_amdgcn_s_setprio(0);
      #pragma unroll
      for (int nt = 0; nt < 4; ++nt)
        #pragma unroll
        for (int r = 0; r < 4; ++r) {
          float pv = __expf(sacc[nt][r]);
          Ps[w * 2304 + (16 + quad * 4 + r) * 72 + nt * 16 + lc] = f2bf_p(pv);
        }
    }

    // O += P V ; l += P . 1   (A = Ps, B = Vs / ones)
    __builtin_amdgcn_s_setprio(1);
    #pragma unroll
    for (int ks = 0; ks < 2; ++ks) {
      bf16x8 pf0 = *(const bf16x8*)(&Ps[w * 2304 + (0  + lc) * 72 + ks * 32 + quad * 8]);
      bf16x8 pf1 = *(const bf16x8*)(&Ps[w * 2304 + (16 + lc) * 72 + ks * 32 + quad * 8]);
      lacc[0] = __builtin_amdgcn_mfma_f32_16x16x32_bf16(pf0, ones, lacc[0], 0, 0, 0);
      lacc[1] = __builtin_amdgcn_mfma_f32_16x16x32_bf16(pf1, ones, lacc[1], 0, 0, 0);
      #pragma unroll
      for (int nt = 0; nt < 4; ++nt) {
        bf16x8 vf = *(const bf16x8*)(Vs + (nt * 16 + lc) * 64 + (((ks * 4 + quad) ^ (lc & 7)) * 8));
        oacc[0][nt] = __builtin_amdgcn_mfma_f32_16x16x32_bf16(pf0, vf, oacc[0][nt], 0, 0, 0);
        oacc[1][nt] = __builtin_amdgcn_mfma_f32_16x16x32_bf16(pf1, vf, oacc[1][nt], 0, 0, 0);
      }
    }
    __builtin_amdgcn_s_setprio(0);
  }

  // epilogue: O = (lhm[h]/l) * oacc -> bf16 [b*1024+t][h*64+d]
  const float hm = lhm[h];
  #pragma unroll
  for (int mt = 0; mt < 2; ++mt) {
    us* Og = O + ((size_t)(b * 1024 + q0 + mt * 16 + quad * 4)) * 1024 + h * 64 + lc;
    #pragma unroll
    for (int r = 0; r < 4; ++r) {
      float inv = hm / lacc[mt][r];
      #pragma unroll
      for (int nt = 0; nt < 4; ++nt)
        Og[(size_t)r * 1024 + nt * 16] = f2bf(oacc[mt][nt][r] * inv);
    }
  }
}

extern "C" void kernel_launch(void* const* d_in, const int* in_sizes, int n_in,
                              void* d_out, int out_size, void* d_ws, size_t ws_size,
                              hipStream_t stream) {
  (void)in_sizes; (void)n_in; (void)out_size; (void)ws_size;
  const float* hs   = (const float*)d_in[0];
  const float* kv   = (const float*)d_in[1];
  const float* mask = (const float*)d_in[2];
  const float* lhm  = (const float*)d_in[3];
  const float* Wq   = (const float*)d_in[4];
  const float* bq   = (const float*)d_in[5];
  const float* Wk   = (const float*)d_in[6];
  const float* bk   = (const float*)d_in[7];
  const float* Wv   = (const float*)d_in[8];
  const float* bv   = (const float*)d_in[9];
  const float* Wo   = (const float*)d_in[10];
  const float* bo   = (const float*)d_in[11];
  float* out = (float*)d_out;

  char* p = (char*)d_ws;
  auto alloc = [&](size_t bytes) { char* r = p; p += (bytes + 255) & ~(size_t)255; return r; };
  us* hsb = (us*)alloc((size_t)B_ * T_ * E_ * 2);        // 16 MB
  us* kvb = (us*)alloc((size_t)B_ * S_ * KVIN_ * 2);     // 4 MB
  us* Wqt = (us*)alloc((size_t)E_ * E_ * 2);             // 2 MB
  us* Wkt = (us*)alloc((size_t)E_ * KVIN_ * 2);          // 0.5 MB
  us* Wvt = (us*)alloc((size_t)E_ * KVIN_ * 2);          // 0.5 MB
  us* Wot = (us*)alloc((size_t)E_ * E_ * 2);             // 2 MB
  us* Kb  = (us*)alloc((size_t)B_ * S_ * E_ * 2);        // 16 MB
  us* Vtb = (us*)alloc((size_t)B_ * S_ * E_ * 2);        // 16 MB
  us* Ob  = (us*)alloc((size_t)B_ * T_ * E_ * 2);        // 16 MB

  // 1. fused conversions + weight transposes (1 launch)
  k_prep<<<3840, 256, 0, stream>>>(hs, hsb, kv, kvb, Wq, Wqt, Wk, Wkt, Wv, Wvt, Wo, Wot);

  // 2. fused K+V projection (shared A-tile). Grid (64, 16).
  k_proj<<<dim3(64, 16), 256, 0, stream>>>(kvb, Wkt, Wvt, bk, bv, Kb, Vtb);

  // 3. attention with fused Q-projection (b fast -> XCD = batch dedups mask+hs+K/V)
  k_attn<<<1024, 256, 0, stream>>>(hsb, Wqt, bq, Kb, Vtb, mask, lhm, Ob);

  // 4. output projection -> fp32
  k_oproj<<<dim3(64, 16), 256, 0, stream>>>(Ob, Wot, bo, out);
}